// Round 18
// baseline (215.222 us; speedup 1.0000x reference)
//
#include <hip/hip_runtime.h>
#include <hip/hip_bf16.h>

typedef unsigned short u16t;
typedef short bf16x8 __attribute__((ext_vector_type(8)));
typedef short bf16x4 __attribute__((ext_vector_type(4)));
typedef float f32x4 __attribute__((ext_vector_type(4)));

#define T_SEQ 4096
#define NH    12
#define HD    64
#define C3    2304
#define CDIM  768
#define STRIP_KV 1024
#define SLOTS 80          // sum over qt=0..31 of ceil((qt+1)/8)
#define SC_F  0.18033688011112042f   // (1/sqrt(64)) * log2(e), folded into Q

__device__ __forceinline__ float bf2f(u16t u) {
  union { unsigned int i; float f; } c; c.i = ((unsigned int)u) << 16; return c.f;
}
__device__ __forceinline__ u16t f2bf(float f) {
  union { float f; unsigned int i; } c; c.f = f;
  unsigned int u = c.i;
  u += 0x7fffu + ((u >> 16) & 1u);   // RNE
  return (u16t)(u >> 16);
}
// Packed f32x2 -> bf16x2 (v_cvt_pk_bf16_f32 on gfx950); low 16 bits = a.
__device__ __forceinline__ unsigned pk2bf(float a, float b) {
  __hip_bfloat162 h = __float22bfloat162_rn(make_float2(a, b));
  union { __hip_bfloat162 h; unsigned u; } c; c.h = h; return c.u;
}
__device__ __forceinline__ void gload16(const u16t* g, u16t* l) {
  __builtin_amdgcn_global_load_lds((const __attribute__((address_space(1))) void*)g,
                                   (__attribute__((address_space(3))) void*)l,
                                   16, 0, 0);
}

// LDS-only barrier (attn only): in-flight global->VGPR prefetch stays
// outstanding.
#define BARRIER_LGKM() __asm__ __volatile__("s_waitcnt lgkmcnt(0)\n\ts_barrier" ::: "memory")

// ---------------------------------------------------------------------------
// Merged prep: z=0 -> Wqkv transpose, z=1 -> Wproj transpose, z=2 -> x
// fp32->bf16 convert (vectorized float4x2 -> 8 bf16).  Inputs are fp32.
// ---------------------------------------------------------------------------
__global__ __launch_bounds__(256) void prep_inputs(const float* __restrict__ x,
                                                   const float* __restrict__ Wqkv,
                                                   const float* __restrict__ Wproj,
                                                   u16t* __restrict__ xbf,
                                                   u16t* __restrict__ WqkvT,
                                                   u16t* __restrict__ WprojT) {
  const int z = blockIdx.z;
  const int tx = threadIdx.x, ty = threadIdx.y;       // block (32,8)
  if (z == 2) {
    const int t = ty * 32 + tx;
    const int n8 = T_SEQ * CDIM / 8;
    const int i = ((int)blockIdx.y * (int)gridDim.x + (int)blockIdx.x) * 256 + t;
    if (i < n8) {
      const float4 a = ((const float4*)x)[2 * i];
      const float4 b = ((const float4*)x)[2 * i + 1];
      union { uint4 u; unsigned w[4]; } o;
      o.w[0] = pk2bf(a.x, a.y); o.w[1] = pk2bf(a.z, a.w);
      o.w[2] = pk2bf(b.x, b.y); o.w[3] = pk2bf(b.z, b.w);
      ((uint4*)xbf)[i] = o.u;
    }
    return;
  }
  __shared__ u16t tile[32][33];
  const int Cc = z ? CDIM : C3;
  if (z && blockIdx.x >= (unsigned)(CDIM / 32)) return;
  const float* in = z ? Wproj : Wqkv;
  u16t* out = z ? WprojT : WqkvT;
  const int c0 = blockIdx.x * 32, r0 = blockIdx.y * 32;
#pragma unroll
  for (int i = 0; i < 32; i += 8)
    tile[ty + i][tx] = f2bf(in[(size_t)(r0 + ty + i) * Cc + c0 + tx]);
  __syncthreads();
#pragma unroll
  for (int i = 0; i < 32; i += 8)
    out[(size_t)(c0 + ty + i) * CDIM + r0 + tx] = tile[tx][ty + i];
}

// ---------------------------------------------------------------------------
// C[M,N] = A[M,K]*B[K,N] + bias[N]; A,Bt bf16 (Bt row-major [N][K]).
// Tile MT x (32*NF), 256 threads, global_load_lds staging, counted-vmcnt
// 3-buffer pipeline (R4), T2 chunk swizzle (R5).  FROZEN at R11/R13 state
// (<128,4> / <128,2>; R12's smaller tiles regressed +14us).
// ---------------------------------------------------------------------------
template <int MT, int NF, bool OUTF32>
__global__ __launch_bounds__(256) void gemm_bt_bias(
    const u16t* __restrict__ A, const u16t* __restrict__ Bt,
    const float* __restrict__ bias, void* __restrict__ Cout,
    int M, int N, int K, int qcols, float qscale) {
  constexpr int BN = 32 * NF;
  constexpr int MI = MT / 32;          // M fragments per wave
  constexpr int LA = MT / 64;          // per-thread A loads per stage
  constexpr int LB = NF / 2;           // per-thread B loads per stage
  constexpr int L  = LA + LB;          // per-thread loads per stage
  __shared__ u16t lA[3][MT * 32];
  __shared__ u16t lB[3][BN * 32];
  const int t = threadIdx.x;
  const int lane = t & 63;
  const int wid  = t >> 6;
  const int quad = lane >> 4, l16 = lane & 15;

  // T1: XCD-aware bijective block swizzle (contiguous tile chunk per XCD).
  const int gx = gridDim.x;
  const int nwg = gx * (int)gridDim.y;
  int bid = (int)blockIdx.y * gx + (int)blockIdx.x;
  if ((nwg & 7) == 0) bid = (bid & 7) * (nwg >> 3) + (bid >> 3);
  const int m0 = (bid / gx) * MT, n0 = (bid % gx) * BN;

  const int wm = (wid >> 1) * (16 * MI), wn = (wid & 1) * (16 * NF);
  // T2 read-side slot: chunk quad of row (16k + l16) lives at slot
  // quad ^ ((l16>>1)&3); *8 elements per chunk.
  const int rswz = (quad ^ ((l16 >> 1) & 3)) * 8;

  f32x4 acc[MI][NF];
#pragma unroll
  for (int i = 0; i < MI; ++i)
#pragma unroll
    for (int j = 0; j < NF; ++j) acc[i][j] = (f32x4){0.f, 0.f, 0.f, 0.f};

  auto stage = [&](int b, int k0) {
#pragma unroll
    for (int rd = 0; rd < LA; ++rd) {
      const int e = rd * 256 + t;
      const int row = e >> 2;
      const int ch  = (e & 3) ^ ((row >> 1) & 3);   // T2 source pre-swizzle
      gload16(A + (size_t)(m0 + row) * K + k0 + ch * 8, &lA[b][e * 8]);
    }
#pragma unroll
    for (int rd = 0; rd < LB; ++rd) {
      const int e = rd * 256 + t;
      const int row = e >> 2;
      const int ch  = (e & 3) ^ ((row >> 1) & 3);
      gload16(Bt + (size_t)(n0 + row) * K + k0 + ch * 8, &lB[b][e * 8]);
    }
  };
  auto compute = [&](int b) {
    bf16x8 af[MI], bfr[NF];
#pragma unroll
    for (int i = 0; i < MI; ++i)
      af[i] = *(const bf16x8*)&lA[b][(wm + i * 16 + l16) * 32 + rswz];
#pragma unroll
    for (int i = 0; i < NF; ++i)
      bfr[i] = *(const bf16x8*)&lB[b][(wn + i * 16 + l16) * 32 + rswz];
#pragma unroll
    for (int i = 0; i < MI; ++i)
#pragma unroll
      for (int j = 0; j < NF; ++j)
        acc[i][j] = __builtin_amdgcn_mfma_f32_16x16x32_bf16(af[i], bfr[j], acc[i][j], 0, 0, 0);
  };

  const int NT = K >> 5;               // K/32 tiles (768 -> 24)
  stage(0, 0);
  stage(1, 32);
  for (int tt = 0; tt < NT; ++tt) {
    if (tt < NT - 1) {
      __asm__ __volatile__("s_waitcnt vmcnt(%0)" :: "n"(L) : "memory");
    } else {
      __asm__ __volatile__("s_waitcnt vmcnt(0)" ::: "memory");
    }
    __builtin_amdgcn_s_barrier();
    __builtin_amdgcn_sched_barrier(0);
    compute(tt % 3);
    if (tt + 2 < NT) stage((tt + 2) % 3, (tt + 2) * 32);
  }

#pragma unroll
  for (int j = 0; j < NF; ++j) {
    const int col = n0 + wn + j * 16 + l16;
    const float bv = bias[col];
    const float cs = (col < qcols) ? qscale : 1.0f;
#pragma unroll
    for (int i = 0; i < MI; ++i) {
      const int rowb = m0 + wm + i * 16 + quad * 4;
#pragma unroll
      for (int r = 0; r < 4; ++r) {
        const float val = (acc[i][j][r] + bv) * cs;
        const size_t idx = (size_t)(rowb + r) * N + col;
        if (OUTF32) ((float*)Cout)[idx] = val;
        else        ((u16t*)Cout)[idx] = f2bf(val);
      }
    }
  }
}

// ---------------------------------------------------------------------------
// Split-KV causal attention -- FINAL (R15/R17 measured best, 213.5-214.3us).
// Structure: 256 thr, 4 waves x 32 q-rows, single K/V LDS buffer (22.5 KB,
// VGPR 64), two lgkm barriers per 64-kv tile, setprio around compute,
// STRIP_KV=1024 (slot math a=qt>>3, b=qt&7, base=(a+1)(4a+b)).
// Probed and REJECTED with counter evidence: tighter launch_bounds (R5:
// spill, 4x), K/V dbuf (R10: occupancy halved, +25us), 8-wave/16-row (R14:
// conflicts +60%, +6us), second V-swizzle key (R16: conflicts -32% but
// read-path perturbed, +17us).  This is a latency-bound local optimum of
// the 5-kernel decomposition; beyond it lies a fused deep-pipelined attn
// rewrite (T3/T4-in-attention), out of scope for this session.
// ---------------------------------------------------------------------------
#define KSTR 88
#define VSTR 88

__global__ __launch_bounds__(256, 4) void attn_partial(const u16t* __restrict__ qkv,
                                                       u16t* __restrict__ pO,
                                                       float* __restrict__ pL) {
  const int h     = blockIdx.x;
  const int strip = blockIdx.y;
  const int qt    = 31 - (int)blockIdx.z;           // heavy q-tiles first
  const int q0 = qt * 128;
  const int kv_begin = strip * STRIP_KV;
  const int kv_end   = q0 + 128;
  if (kv_begin >= kv_end) return;                   // strip above diagonal
  const int kv_stop = (kv_begin + STRIP_KV < kv_end) ? kv_begin + STRIP_KV : kv_end;
  const int a = qt >> 3, b = qt & 7;
  const int slot = (a + 1) * (4 * a + b) + strip;

  __shared__ u16t lK[64 * KSTR];        // [kv][d]
  __shared__ u16t lVt[64 * VSTR];       // [d][kv^swz] (reused as epilogue scratch)

  const int t = threadIdx.x;
  const int lane = t & 63;
  const int wid  = t >> 6;
  const int quad = lane >> 4, l16 = lane & 15;
  const int wr = q0 + wid * 32;                     // wave owns 32 q rows

  const int krow = t >> 3, kcol = (t & 7) * 8;
  const int vk0 = 4 * (t >> 4);
  const int vd0 = 4 * (t & 15);
  const int vswz = (t & 3) << 3;
  const u16t* Kbase = qkv + CDIM + h * HD;
  const u16t* Vbase = qkv + 2 * CDIM + h * HD;

  // Q fragments (pre-scaled by SC in gemm1's epilogue)
  bf16x8 qf[2][2];
#pragma unroll
  for (int qn = 0; qn < 2; ++qn) {
    const int row = wr + qn * 16 + l16;
#pragma unroll
    for (int kd = 0; kd < 2; ++kd)
      qf[qn][kd] = *(const bf16x8*)(qkv + (size_t)row * C3 + h * HD + kd * 32 + quad * 8);
  }

  f32x4 oaccT[4][2];                 // O^T tiles: [dn][qn], row=d, col=q
  f32x4 laccT[2];                    // l via ones-MFMA (all 4 regs identical)
#pragma unroll
  for (int dn = 0; dn < 4; ++dn)
#pragma unroll
    for (int qn = 0; qn < 2; ++qn) oaccT[dn][qn] = (f32x4){0.f, 0.f, 0.f, 0.f};
#pragma unroll
  for (int qn = 0; qn < 2; ++qn) laccT[qn] = (f32x4){0.f, 0.f, 0.f, 0.f};
  bf16x4 ones4;
#pragma unroll
  for (int i = 0; i < 4; ++i) ones4[i] = (short)0x3F80;  // bf16 1.0

  const int pswz = ((l16 >> 2) & 3) << 3;          // V read-side swizzle key

  uint4 kreg0, kreg1;
  union { uint2 u; u16t hw[4]; } vreg[4];

#define LOAD_TILE(KV0)                                                        \
  do {                                                                        \
    kreg0 = *(const uint4*)(Kbase + (size_t)((KV0) + krow) * C3 + kcol);      \
    kreg1 = *(const uint4*)(Kbase + (size_t)((KV0) + krow + 32) * C3 + kcol); \
    _Pragma("unroll")                                                         \
    for (int i = 0; i < 4; ++i)                                               \
      vreg[i].u = *(const uint2*)(Vbase + (size_t)((KV0) + vk0 + i) * C3 + vd0); \
  } while (0)

#define STORE_TILE()                                                          \
  do {                                                                        \
    *(uint4*)&lK[krow * KSTR + kcol] = kreg0;                                 \
    *(uint4*)&lK[(krow + 32) * KSTR + kcol] = kreg1;                          \
    _Pragma("unroll")                                                         \
    for (int j = 0; j < 4; ++j) {                                             \
      union { uint2 u; u16t hw[4]; } w;                                       \
      w.hw[0] = vreg[0].hw[j]; w.hw[1] = vreg[1].hw[j];                       \
      w.hw[2] = vreg[2].hw[j]; w.hw[3] = vreg[3].hw[j];                       \
      *(uint2*)&lVt[(vd0 + j) * VSTR + (vk0 ^ vswz)] = w.u;                   \
    }                                                                         \
  } while (0)

  LOAD_TILE(kv_begin);
  STORE_TILE();

  for (int kv0 = kv_begin; kv0 < kv_stop; kv0 += 64) {
    const bool havenext = (kv0 + 64 < kv_stop);
    if (havenext) LOAD_TILE(kv0 + 64);   // stays in flight across compute
    BARRIER_LGKM();

    if (kv0 <= wr + 31) {                // wave-uniform skip of masked tiles
      __builtin_amdgcn_s_setprio(1);
      // ---- S^T = K · Q^T (Q pre-scaled; exp2 arg is ready) ----
      f32x4 sacc[4][2];                  // [kvt][qn]
#pragma unroll
      for (int kvt = 0; kvt < 4; ++kvt) {
        bf16x8 kf0 = *(const bf16x8*)&lK[(kvt * 16 + l16) * KSTR + quad * 8];
        bf16x8 kf1 = *(const bf16x8*)&lK[(kvt * 16 + l16) * KSTR + 32 + quad * 8];
#pragma unroll
        for (int qn = 0; qn < 2; ++qn) {
          f32x4 s = (f32x4){0.f, 0.f, 0.f, 0.f};
          s = __builtin_amdgcn_mfma_f32_16x16x32_bf16(kf0, qf[qn][0], s, 0, 0, 0);
          s = __builtin_amdgcn_mfma_f32_16x16x32_bf16(kf1, qf[qn][1], s, 0, 0, 0);
          sacc[kvt][qn] = s;
        }
      }
      const bool need_mask = (kv0 + 63 > wr);
      // ---- P^T = exp2(S^T) -> packed bf16 B-operand registers ----
      bf16x4 pbf[4][2];
#pragma unroll
      for (int kvt = 0; kvt < 4; ++kvt)
#pragma unroll
        for (int qn = 0; qn < 2; ++qn) {
          const int qg = wr + qn * 16 + l16;
          float pv[4];
#pragma unroll
          for (int r = 0; r < 4; ++r) {
            const int kvg = kv0 + kvt * 16 + quad * 4 + r;
            float p = __builtin_amdgcn_exp2f(sacc[kvt][qn][r]);
            if (need_mask && (kvg > qg)) p = 0.f;
            pv[r] = p;
          }
          union { bf16x4 v; unsigned u[2]; } pw;
          pw.u[0] = pk2bf(pv[0], pv[1]);
          pw.u[1] = pk2bf(pv[2], pv[3]);
          pbf[kvt][qn] = pw.v;
        }
      // ---- O^T += V^T · P^T ; l += ones · P^T (both pure MFMA) ----
#pragma unroll
      for (int kvt = 0; kvt < 4; ++kvt) {
        const int kvcol = (kvt * 16 + quad * 4) ^ pswz;
#pragma unroll
        for (int qn = 0; qn < 2; ++qn)
          laccT[qn] = __builtin_amdgcn_mfma_f32_16x16x16bf16_1k(
              ones4, pbf[kvt][qn], laccT[qn], 0, 0, 0);
#pragma unroll
        for (int dn = 0; dn < 4; ++dn) {
          bf16x4 vf = *(const bf16x4*)&lVt[(dn * 16 + l16) * VSTR + kvcol];
#pragma unroll
          for (int qn = 0; qn < 2; ++qn)
            oaccT[dn][qn] = __builtin_amdgcn_mfma_f32_16x16x16bf16_1k(
                vf, pbf[kvt][qn], oaccT[dn][qn], 0, 0, 0);
        }
      }
      __builtin_amdgcn_s_setprio(0);
    }
    BARRIER_LGKM();                      // all reads of LDS tile kv0 done
    if (havenext) STORE_TILE();
  }

  // ---- epilogue: O^T -> [q][d] via per-wave LDS transpose; packed converts.
  {
    u16t* scr = &lVt[wid * 16 * 80];     // 16 q-rows x stride 80 per wave
    u16t* po = pO + ((size_t)h * SLOTS + slot) * 128 * HD;
    float* pl = pL + ((size_t)h * SLOTS + slot) * 128;
#pragma unroll
    for (int qn = 0; qn < 2; ++qn) {
#pragma unroll
      for (int dn = 0; dn < 4; ++dn) {
        union { bf16x4 v; unsigned u[2]; } w;
        w.u[0] = pk2bf(oaccT[dn][qn][0], oaccT[dn][qn][1]);
        w.u[1] = pk2bf(oaccT[dn][qn][2], oaccT[dn][qn][3]);
        *(bf16x4*)&scr[l16 * 80 + dn * 16 + quad * 4] = w.v;
      }
      __asm__ __volatile__("s_waitcnt lgkmcnt(0)" ::: "memory");
      const int ql = wid * 32 + qn * 16 + l16;
      uint4 w0 = *(const uint4*)&scr[l16 * 80 + quad * 16];
      uint4 w1 = *(const uint4*)&scr[l16 * 80 + quad * 16 + 8];
      u16t* dst = po + (size_t)ql * HD + quad * 16;
      *(uint4*)dst = w0;
      *(uint4*)(dst + 8) = w1;
      if (quad == 0) pl[ql] = laccT[qn][0];
      __asm__ __volatile__("s_waitcnt lgkmcnt(0)" ::: "memory");
    }
  }
#undef LOAD_TILE
#undef STORE_TILE
}

// ---------------------------------------------------------------------------
// 8-wide: each thread normalizes 8 consecutive d of one (q,h).
// STRIP_KV=1024 slot math: a=qt>>3, b=qt&7, base=(a+1)(4a+b), ns=a+1.
// ---------------------------------------------------------------------------
__global__ __launch_bounds__(256) void attn_normalize(const u16t* __restrict__ pO,
                                                      const float* __restrict__ pL,
                                                      u16t* __restrict__ y) {
  const int i = blockIdx.x * 256 + threadIdx.x;   // over T*C/8
  const int q = i / (CDIM / 8), c8 = (i % (CDIM / 8)) * 8;
  const int h = c8 >> 6, d = c8 & 63;
  const int qt = q >> 7, ql = q & 127;
  const int a = qt >> 3, b = qt & 7;
  const int base = (a + 1) * (4 * a + b);
  const int ns = a + 1;                            // ceil((qt+1)/8)
  float o[8] = {0.f, 0.f, 0.f, 0.f, 0.f, 0.f, 0.f, 0.f};
  float l = 0.f;
  for (int s = 0; s < ns; ++s) {
    const size_t sl = (size_t)h * SLOTS + base + s;
    union { uint4 u; u16t hw[8]; } v;
    v.u = *(const uint4*)&pO[(sl * 128 + ql) * HD + d];
#pragma unroll
    for (int j = 0; j < 8; ++j) o[j] += bf2f(v.hw[j]);
    l += pL[sl * 128 + ql];
  }
  const float rl = 1.0f / l;
  union { uint4 u; unsigned w[4]; } wv;
#pragma unroll
  for (int j = 0; j < 4; ++j)
    wv.w[j] = pk2bf(o[2 * j] * rl, o[2 * j + 1] * rl);
  *(uint4*)&y[(size_t)q * CDIM + c8] = wv.u;
}

// ---------------------------------------------------------------------------
extern "C" void kernel_launch(void* const* d_in, const int* in_sizes, int n_in,
                              void* d_out, int out_size, void* d_ws, size_t ws_size,
                              hipStream_t stream) {
  const float* x     = (const float*)d_in[0];
  // d_in[1] = mask (unused — causal mask applied analytically)
  const float* Wqkv  = (const float*)d_in[2];
  const float* bqkv  = (const float*)d_in[3];
  const float* Wproj = (const float*)d_in[4];
  const float* bproj = (const float*)d_in[5];

  u16t* qkv    = (u16t*)d_ws;                     // [4096][2304] bf16
  u16t* ybuf   = qkv    + (size_t)T_SEQ * C3;     // [4096][768]  bf16 (x, then attn out)
  u16t* WqkvT  = ybuf   + (size_t)T_SEQ * CDIM;   // [2304][768]  bf16
  u16t* WprojT = WqkvT  + (size_t)C3 * CDIM;      // [768][768]   bf16
  u16t* pO     = WprojT + (size_t)CDIM * CDIM;    // [12][80][128][64] bf16
  float* pL    = (float*)(pO + (size_t)NH * SLOTS * 128 * HD);  // [12][80][128] f32

  prep_inputs<<<dim3(C3 / 32, CDIM / 32, 3), dim3(32, 8), 0, stream>>>(
      x, Wqkv, Wproj, ybuf, WqkvT, WprojT);
  gemm_bt_bias<128, 4, false><<<dim3(C3 / 128, T_SEQ / 128), 256, 0, stream>>>(
      ybuf, WqkvT, bqkv, qkv, T_SEQ, C3, CDIM, CDIM, SC_F);
  attn_partial<<<dim3(NH, T_SEQ / STRIP_KV, T_SEQ / 128), 256, 0, stream>>>(qkv, pO, pL);
  attn_normalize<<<(T_SEQ * CDIM / 8) / 256, 256, 0, stream>>>(pO, pL, ybuf);
  gemm_bt_bias<128, 2, true><<<dim3(CDIM / 64, T_SEQ / 128), 256, 0, stream>>>(
      ybuf, WprojT, bproj, d_out, T_SEQ, CDIM, CDIM, 0, 1.0f);
}

// Round 19
// 212.713 us; speedup vs baseline: 1.0118x; 1.0118x over previous
//
#include <hip/hip_runtime.h>
#include <hip/hip_bf16.h>

typedef unsigned short u16t;
typedef short bf16x8 __attribute__((ext_vector_type(8)));
typedef short bf16x4 __attribute__((ext_vector_type(4)));
typedef float f32x4 __attribute__((ext_vector_type(4)));

#define T_SEQ 4096
#define NH    12
#define HD    64
#define C3    2304
#define CDIM  768
#define STRIP_KV 1024
#define SLOTS 80          // sum over qt=0..31 of ceil((qt+1)/8)
#define SC_F  0.18033688011112042f   // (1/sqrt(64)) * log2(e), folded into Q

__device__ __forceinline__ float bf2f(u16t u) {
  union { unsigned int i; float f; } c; c.i = ((unsigned int)u) << 16; return c.f;
}
__device__ __forceinline__ u16t f2bf(float f) {
  union { float f; unsigned int i; } c; c.f = f;
  unsigned int u = c.i;
  u += 0x7fffu + ((u >> 16) & 1u);   // RNE
  return (u16t)(u >> 16);
}
// Packed f32x2 -> bf16x2 (v_cvt_pk_bf16_f32 on gfx950); low 16 bits = a.
__device__ __forceinline__ unsigned pk2bf(float a, float b) {
  __hip_bfloat162 h = __float22bfloat162_rn(make_float2(a, b));
  union { __hip_bfloat162 h; unsigned u; } c; c.h = h; return c.u;
}
__device__ __forceinline__ void gload16(const u16t* g, u16t* l) {
  __builtin_amdgcn_global_load_lds((const __attribute__((address_space(1))) void*)g,
                                   (__attribute__((address_space(3))) void*)l,
                                   16, 0, 0);
}

// LDS-only barrier (attn only): in-flight global->VGPR prefetch stays
// outstanding.
#define BARRIER_LGKM() __asm__ __volatile__("s_waitcnt lgkmcnt(0)\n\ts_barrier" ::: "memory")

// ---------------------------------------------------------------------------
// Merged prep: z=0 -> Wqkv transpose, z=1 -> Wproj transpose, z=2 -> x
// fp32->bf16 convert (vectorized float4x2 -> 8 bf16).  Inputs are fp32.
// ---------------------------------------------------------------------------
__global__ __launch_bounds__(256) void prep_inputs(const float* __restrict__ x,
                                                   const float* __restrict__ Wqkv,
                                                   const float* __restrict__ Wproj,
                                                   u16t* __restrict__ xbf,
                                                   u16t* __restrict__ WqkvT,
                                                   u16t* __restrict__ WprojT) {
  const int z = blockIdx.z;
  const int tx = threadIdx.x, ty = threadIdx.y;       // block (32,8)
  if (z == 2) {
    const int t = ty * 32 + tx;
    const int n8 = T_SEQ * CDIM / 8;
    const int i = ((int)blockIdx.y * (int)gridDim.x + (int)blockIdx.x) * 256 + t;
    if (i < n8) {
      const float4 a = ((const float4*)x)[2 * i];
      const float4 b = ((const float4*)x)[2 * i + 1];
      union { uint4 u; unsigned w[4]; } o;
      o.w[0] = pk2bf(a.x, a.y); o.w[1] = pk2bf(a.z, a.w);
      o.w[2] = pk2bf(b.x, b.y); o.w[3] = pk2bf(b.z, b.w);
      ((uint4*)xbf)[i] = o.u;
    }
    return;
  }
  __shared__ u16t tile[32][33];
  const int Cc = z ? CDIM : C3;
  if (z && blockIdx.x >= (unsigned)(CDIM / 32)) return;
  const float* in = z ? Wproj : Wqkv;
  u16t* out = z ? WprojT : WqkvT;
  const int c0 = blockIdx.x * 32, r0 = blockIdx.y * 32;
#pragma unroll
  for (int i = 0; i < 32; i += 8)
    tile[ty + i][tx] = f2bf(in[(size_t)(r0 + ty + i) * Cc + c0 + tx]);
  __syncthreads();
#pragma unroll
  for (int i = 0; i < 32; i += 8)
    out[(size_t)(c0 + ty + i) * CDIM + r0 + tx] = tile[tx][ty + i];
}

// ---------------------------------------------------------------------------
// C[M,N] = A[M,K]*B[K,N] + bias[N]; A,Bt bf16 (Bt row-major [N][K]).
// Tile MT x (32*NF), 256 threads, global_load_lds staging, counted-vmcnt
// DEPTH-buffer pipeline + T2 chunk swizzle.
// R19: DEPTH template param.  gemm1 stays DEPTH=3 (4 buffers = 64KB = the
// m132 2-blocks/CU LDS trap at its 2.25/CU grid).  gemm2 -> DEPTH=4
// (48KB, still 3/CU by LDS; its grid is only 1.5 blocks/CU, so per-wave
// ILP is the only latency-hiding lever left -- R10/R12 proved occupancy
// moves fail).  Steady-state wait vmcnt(2L): 3 stages in flight per wave,
// 2x the latency coverage of DEPTH=3.  Drain: outstanding at iter tt =
// min(NT,tt+3)-tt -> vmcnt(2L)/vmcnt(L)/vmcnt(0) for tt<NT-2 / NT-2 / NT-1.
// Overwrite-safety: stage(tt+3) writes buf (tt-1)%4 whose readers' lgkm-
// waited MFMAs completed before this iter's barrier (same proof as R4).
// ---------------------------------------------------------------------------
template <int MT, int NF, bool OUTF32, int DEPTH>
__global__ __launch_bounds__(256) void gemm_bt_bias(
    const u16t* __restrict__ A, const u16t* __restrict__ Bt,
    const float* __restrict__ bias, void* __restrict__ Cout,
    int M, int N, int K, int qcols, float qscale) {
  constexpr int BN = 32 * NF;
  constexpr int MI = MT / 32;          // M fragments per wave
  constexpr int LA = MT / 64;          // per-thread A loads per stage
  constexpr int LB = NF / 2;           // per-thread B loads per stage
  constexpr int L  = LA + LB;          // per-thread loads per stage
  __shared__ u16t lA[DEPTH][MT * 32];
  __shared__ u16t lB[DEPTH][BN * 32];
  const int t = threadIdx.x;
  const int lane = t & 63;
  const int wid  = t >> 6;
  const int quad = lane >> 4, l16 = lane & 15;

  // T1: XCD-aware bijective block swizzle (contiguous tile chunk per XCD).
  const int gx = gridDim.x;
  const int nwg = gx * (int)gridDim.y;
  int bid = (int)blockIdx.y * gx + (int)blockIdx.x;
  if ((nwg & 7) == 0) bid = (bid & 7) * (nwg >> 3) + (bid >> 3);
  const int m0 = (bid / gx) * MT, n0 = (bid % gx) * BN;

  const int wm = (wid >> 1) * (16 * MI), wn = (wid & 1) * (16 * NF);
  // T2 read-side slot: chunk quad of row (16k + l16) lives at slot
  // quad ^ ((l16>>1)&3); *8 elements per chunk.
  const int rswz = (quad ^ ((l16 >> 1) & 3)) * 8;

  f32x4 acc[MI][NF];
#pragma unroll
  for (int i = 0; i < MI; ++i)
#pragma unroll
    for (int j = 0; j < NF; ++j) acc[i][j] = (f32x4){0.f, 0.f, 0.f, 0.f};

  auto stage = [&](int b, int k0) {
#pragma unroll
    for (int rd = 0; rd < LA; ++rd) {
      const int e = rd * 256 + t;
      const int row = e >> 2;
      const int ch  = (e & 3) ^ ((row >> 1) & 3);   // T2 source pre-swizzle
      gload16(A + (size_t)(m0 + row) * K + k0 + ch * 8, &lA[b][e * 8]);
    }
#pragma unroll
    for (int rd = 0; rd < LB; ++rd) {
      const int e = rd * 256 + t;
      const int row = e >> 2;
      const int ch  = (e & 3) ^ ((row >> 1) & 3);
      gload16(Bt + (size_t)(n0 + row) * K + k0 + ch * 8, &lB[b][e * 8]);
    }
  };
  auto compute = [&](int b) {
    bf16x8 af[MI], bfr[NF];
#pragma unroll
    for (int i = 0; i < MI; ++i)
      af[i] = *(const bf16x8*)&lA[b][(wm + i * 16 + l16) * 32 + rswz];
#pragma unroll
    for (int i = 0; i < NF; ++i)
      bfr[i] = *(const bf16x8*)&lB[b][(wn + i * 16 + l16) * 32 + rswz];
#pragma unroll
    for (int i = 0; i < MI; ++i)
#pragma unroll
      for (int j = 0; j < NF; ++j)
        acc[i][j] = __builtin_amdgcn_mfma_f32_16x16x32_bf16(af[i], bfr[j], acc[i][j], 0, 0, 0);
  };

  const int NT = K >> 5;               // K/32 tiles (768 -> 24)
  stage(0, 0);
  stage(1, 32);
  if (DEPTH >= 4 && NT > 2) stage(2, 64);
  for (int tt = 0; tt < NT; ++tt) {
    if (DEPTH >= 4) {
      if (tt < NT - 2) {
        __asm__ __volatile__("s_waitcnt vmcnt(%0)" :: "n"(2 * L) : "memory");
      } else if (tt == NT - 2) {
        __asm__ __volatile__("s_waitcnt vmcnt(%0)" :: "n"(L) : "memory");
      } else {
        __asm__ __volatile__("s_waitcnt vmcnt(0)" ::: "memory");
      }
    } else {
      if (tt < NT - 1) {
        __asm__ __volatile__("s_waitcnt vmcnt(%0)" :: "n"(L) : "memory");
      } else {
        __asm__ __volatile__("s_waitcnt vmcnt(0)" ::: "memory");
      }
    }
    __builtin_amdgcn_s_barrier();
    __builtin_amdgcn_sched_barrier(0);
    compute(tt % DEPTH);
    if (tt + DEPTH - 1 < NT) stage((tt + DEPTH - 1) % DEPTH, (tt + DEPTH - 1) * 32);
  }

#pragma unroll
  for (int j = 0; j < NF; ++j) {
    const int col = n0 + wn + j * 16 + l16;
    const float bv = bias[col];
    const float cs = (col < qcols) ? qscale : 1.0f;
#pragma unroll
    for (int i = 0; i < MI; ++i) {
      const int rowb = m0 + wm + i * 16 + quad * 4;
#pragma unroll
      for (int r = 0; r < 4; ++r) {
        const float val = (acc[i][j][r] + bv) * cs;
        const size_t idx = (size_t)(rowb + r) * N + col;
        if (OUTF32) ((float*)Cout)[idx] = val;
        else        ((u16t*)Cout)[idx] = f2bf(val);
      }
    }
  }
}

// ---------------------------------------------------------------------------
// Split-KV causal attention -- FROZEN at R15/R17 measured best (213.5-215.2).
// Structure: 256 thr, 4 waves x 32 q-rows, single K/V LDS buffer (22.5 KB,
// VGPR 64), two lgkm barriers per 64-kv tile, setprio around compute,
// STRIP_KV=1024 (slot math a=qt>>3, b=qt&7, base=(a+1)(4a+b)).
// Probed and REJECTED with counter evidence: tighter launch_bounds (R5:
// spill, 4x), K/V dbuf (R10: occupancy halved, +25us), 8-wave/16-row (R14:
// conflicts +60%, +6us), second V-swizzle key (R16: conflicts -32% but
// read-path perturbed, +17us).
// ---------------------------------------------------------------------------
#define KSTR 88
#define VSTR 88

__global__ __launch_bounds__(256, 4) void attn_partial(const u16t* __restrict__ qkv,
                                                       u16t* __restrict__ pO,
                                                       float* __restrict__ pL) {
  const int h     = blockIdx.x;
  const int strip = blockIdx.y;
  const int qt    = 31 - (int)blockIdx.z;           // heavy q-tiles first
  const int q0 = qt * 128;
  const int kv_begin = strip * STRIP_KV;
  const int kv_end   = q0 + 128;
  if (kv_begin >= kv_end) return;                   // strip above diagonal
  const int kv_stop = (kv_begin + STRIP_KV < kv_end) ? kv_begin + STRIP_KV : kv_end;
  const int a = qt >> 3, b = qt & 7;
  const int slot = (a + 1) * (4 * a + b) + strip;

  __shared__ u16t lK[64 * KSTR];        // [kv][d]
  __shared__ u16t lVt[64 * VSTR];       // [d][kv^swz] (reused as epilogue scratch)

  const int t = threadIdx.x;
  const int lane = t & 63;
  const int wid  = t >> 6;
  const int quad = lane >> 4, l16 = lane & 15;
  const int wr = q0 + wid * 32;                     // wave owns 32 q rows

  const int krow = t >> 3, kcol = (t & 7) * 8;
  const int vk0 = 4 * (t >> 4);
  const int vd0 = 4 * (t & 15);
  const int vswz = (t & 3) << 3;
  const u16t* Kbase = qkv + CDIM + h * HD;
  const u16t* Vbase = qkv + 2 * CDIM + h * HD;

  // Q fragments (pre-scaled by SC in gemm1's epilogue)
  bf16x8 qf[2][2];
#pragma unroll
  for (int qn = 0; qn < 2; ++qn) {
    const int row = wr + qn * 16 + l16;
#pragma unroll
    for (int kd = 0; kd < 2; ++kd)
      qf[qn][kd] = *(const bf16x8*)(qkv + (size_t)row * C3 + h * HD + kd * 32 + quad * 8);
  }

  f32x4 oaccT[4][2];                 // O^T tiles: [dn][qn], row=d, col=q
  f32x4 laccT[2];                    // l via ones-MFMA (all 4 regs identical)
#pragma unroll
  for (int dn = 0; dn < 4; ++dn)
#pragma unroll
    for (int qn = 0; qn < 2; ++qn) oaccT[dn][qn] = (f32x4){0.f, 0.f, 0.f, 0.f};
#pragma unroll
  for (int qn = 0; qn < 2; ++qn) laccT[qn] = (f32x4){0.f, 0.f, 0.f, 0.f};
  bf16x4 ones4;
#pragma unroll
  for (int i = 0; i < 4; ++i) ones4[i] = (short)0x3F80;  // bf16 1.0

  const int pswz = ((l16 >> 2) & 3) << 3;          // V read-side swizzle key

  uint4 kreg0, kreg1;
  union { uint2 u; u16t hw[4]; } vreg[4];

#define LOAD_TILE(KV0)                                                        \
  do {                                                                        \
    kreg0 = *(const uint4*)(Kbase + (size_t)((KV0) + krow) * C3 + kcol);      \
    kreg1 = *(const uint4*)(Kbase + (size_t)((KV0) + krow + 32) * C3 + kcol); \
    _Pragma("unroll")                                                         \
    for (int i = 0; i < 4; ++i)                                               \
      vreg[i].u = *(const uint2*)(Vbase + (size_t)((KV0) + vk0 + i) * C3 + vd0); \
  } while (0)

#define STORE_TILE()                                                          \
  do {                                                                        \
    *(uint4*)&lK[krow * KSTR + kcol] = kreg0;                                 \
    *(uint4*)&lK[(krow + 32) * KSTR + kcol] = kreg1;                          \
    _Pragma("unroll")                                                         \
    for (int j = 0; j < 4; ++j) {                                             \
      union { uint2 u; u16t hw[4]; } w;                                       \
      w.hw[0] = vreg[0].hw[j]; w.hw[1] = vreg[1].hw[j];                       \
      w.hw[2] = vreg[2].hw[j]; w.hw[3] = vreg[3].hw[j];                       \
      *(uint2*)&lVt[(vd0 + j) * VSTR + (vk0 ^ vswz)] = w.u;                   \
    }                                                                         \
  } while (0)

  LOAD_TILE(kv_begin);
  STORE_TILE();

  for (int kv0 = kv_begin; kv0 < kv_stop; kv0 += 64) {
    const bool havenext = (kv0 + 64 < kv_stop);
    if (havenext) LOAD_TILE(kv0 + 64);   // stays in flight across compute
    BARRIER_LGKM();

    if (kv0 <= wr + 31) {                // wave-uniform skip of masked tiles
      __builtin_amdgcn_s_setprio(1);
      // ---- S^T = K · Q^T (Q pre-scaled; exp2 arg is ready) ----
      f32x4 sacc[4][2];                  // [kvt][qn]
#pragma unroll
      for (int kvt = 0; kvt < 4; ++kvt) {
        bf16x8 kf0 = *(const bf16x8*)&lK[(kvt * 16 + l16) * KSTR + quad * 8];
        bf16x8 kf1 = *(const bf16x8*)&lK[(kvt * 16 + l16) * KSTR + 32 + quad * 8];
#pragma unroll
        for (int qn = 0; qn < 2; ++qn) {
          f32x4 s = (f32x4){0.f, 0.f, 0.f, 0.f};
          s = __builtin_amdgcn_mfma_f32_16x16x32_bf16(kf0, qf[qn][0], s, 0, 0, 0);
          s = __builtin_amdgcn_mfma_f32_16x16x32_bf16(kf1, qf[qn][1], s, 0, 0, 0);
          sacc[kvt][qn] = s;
        }
      }
      const bool need_mask = (kv0 + 63 > wr);
      // ---- P^T = exp2(S^T) -> packed bf16 B-operand registers ----
      bf16x4 pbf[4][2];
#pragma unroll
      for (int kvt = 0; kvt < 4; ++kvt)
#pragma unroll
        for (int qn = 0; qn < 2; ++qn) {
          const int qg = wr + qn * 16 + l16;
          float pv[4];
#pragma unroll
          for (int r = 0; r < 4; ++r) {
            const int kvg = kv0 + kvt * 16 + quad * 4 + r;
            float p = __builtin_amdgcn_exp2f(sacc[kvt][qn][r]);
            if (need_mask && (kvg > qg)) p = 0.f;
            pv[r] = p;
          }
          union { bf16x4 v; unsigned u[2]; } pw;
          pw.u[0] = pk2bf(pv[0], pv[1]);
          pw.u[1] = pk2bf(pv[2], pv[3]);
          pbf[kvt][qn] = pw.v;
        }
      // ---- O^T += V^T · P^T ; l += ones · P^T (both pure MFMA) ----
#pragma unroll
      for (int kvt = 0; kvt < 4; ++kvt) {
        const int kvcol = (kvt * 16 + quad * 4) ^ pswz;
#pragma unroll
        for (int qn = 0; qn < 2; ++qn)
          laccT[qn] = __builtin_amdgcn_mfma_f32_16x16x16bf16_1k(
              ones4, pbf[kvt][qn], laccT[qn], 0, 0, 0);
#pragma unroll
        for (int dn = 0; dn < 4; ++dn) {
          bf16x4 vf = *(const bf16x4*)&lVt[(dn * 16 + l16) * VSTR + kvcol];
#pragma unroll
          for (int qn = 0; qn < 2; ++qn)
            oaccT[dn][qn] = __builtin_amdgcn_mfma_f32_16x16x16bf16_1k(
                vf, pbf[kvt][qn], oaccT[dn][qn], 0, 0, 0);
        }
      }
      __builtin_amdgcn_s_setprio(0);
    }
    BARRIER_LGKM();                      // all reads of LDS tile kv0 done
    if (havenext) STORE_TILE();
  }

  // ---- epilogue: O^T -> [q][d] via per-wave LDS transpose; packed converts.
  {
    u16t* scr = &lVt[wid * 16 * 80];     // 16 q-rows x stride 80 per wave
    u16t* po = pO + ((size_t)h * SLOTS + slot) * 128 * HD;
    float* pl = pL + ((size_t)h * SLOTS + slot) * 128;
#pragma unroll
    for (int qn = 0; qn < 2; ++qn) {
#pragma unroll
      for (int dn = 0; dn < 4; ++dn) {
        union { bf16x4 v; unsigned u[2]; } w;
        w.u[0] = pk2bf(oaccT[dn][qn][0], oaccT[dn][qn][1]);
        w.u[1] = pk2bf(oaccT[dn][qn][2], oaccT[dn][qn][3]);
        *(bf16x4*)&scr[l16 * 80 + dn * 16 + quad * 4] = w.v;
      }
      __asm__ __volatile__("s_waitcnt lgkmcnt(0)" ::: "memory");
      const int ql = wid * 32 + qn * 16 + l16;
      uint4 w0 = *(const uint4*)&scr[l16 * 80 + quad * 16];
      uint4 w1 = *(const uint4*)&scr[l16 * 80 + quad * 16 + 8];
      u16t* dst = po + (size_t)ql * HD + quad * 16;
      *(uint4*)dst = w0;
      *(uint4*)(dst + 8) = w1;
      if (quad == 0) pl[ql] = laccT[qn][0];
      __asm__ __volatile__("s_waitcnt lgkmcnt(0)" ::: "memory");
    }
  }
#undef LOAD_TILE
#undef STORE_TILE
}

// ---------------------------------------------------------------------------
// 8-wide: each thread normalizes 8 consecutive d of one (q,h).
// STRIP_KV=1024 slot math: a=qt>>3, b=qt&7, base=(a+1)(4a+b), ns=a+1.
// ---------------------------------------------------------------------------
__global__ __launch_bounds__(256) void attn_normalize(const u16t* __restrict__ pO,
                                                      const float* __restrict__ pL,
                                                      u16t* __restrict__ y) {
  const int i = blockIdx.x * 256 + threadIdx.x;   // over T*C/8
  const int q = i / (CDIM / 8), c8 = (i % (CDIM / 8)) * 8;
  const int h = c8 >> 6, d = c8 & 63;
  const int qt = q >> 7, ql = q & 127;
  const int a = qt >> 3, b = qt & 7;
  const int base = (a + 1) * (4 * a + b);
  const int ns = a + 1;                            // ceil((qt+1)/8)
  float o[8] = {0.f, 0.f, 0.f, 0.f, 0.f, 0.f, 0.f, 0.f};
  float l = 0.f;
  for (int s = 0; s < ns; ++s) {
    const size_t sl = (size_t)h * SLOTS + base + s;
    union { uint4 u; u16t hw[8]; } v;
    v.u = *(const uint4*)&pO[(sl * 128 + ql) * HD + d];
#pragma unroll
    for (int j = 0; j < 8; ++j) o[j] += bf2f(v.hw[j]);
    l += pL[sl * 128 + ql];
  }
  const float rl = 1.0f / l;
  union { uint4 u; unsigned w[4]; } wv;
#pragma unroll
  for (int j = 0; j < 4; ++j)
    wv.w[j] = pk2bf(o[2 * j] * rl, o[2 * j + 1] * rl);
  *(uint4*)&y[(size_t)q * CDIM + c8] = wv.u;
}

// ---------------------------------------------------------------------------
extern "C" void kernel_launch(void* const* d_in, const int* in_sizes, int n_in,
                              void* d_out, int out_size, void* d_ws, size_t ws_size,
                              hipStream_t stream) {
  const float* x     = (const float*)d_in[0];
  // d_in[1] = mask (unused — causal mask applied analytically)
  const float* Wqkv  = (const float*)d_in[2];
  const float* bqkv  = (const float*)d_in[3];
  const float* Wproj = (const float*)d_in[4];
  const float* bproj = (const float*)d_in[5];

  u16t* qkv    = (u16t*)d_ws;                     // [4096][2304] bf16
  u16t* ybuf   = qkv    + (size_t)T_SEQ * C3;     // [4096][768]  bf16 (x, then attn out)
  u16t* WqkvT  = ybuf   + (size_t)T_SEQ * CDIM;   // [2304][768]  bf16
  u16t* WprojT = WqkvT  + (size_t)C3 * CDIM;      // [768][768]   bf16
  u16t* pO     = WprojT + (size_t)CDIM * CDIM;    // [12][80][128][64] bf16
  float* pL    = (float*)(pO + (size_t)NH * SLOTS * 128 * HD);  // [12][80][128] f32

  prep_inputs<<<dim3(C3 / 32, CDIM / 32, 3), dim3(32, 8), 0, stream>>>(
      x, Wqkv, Wproj, ybuf, WqkvT, WprojT);
  gemm_bt_bias<128, 4, false, 3><<<dim3(C3 / 128, T_SEQ / 128), 256, 0, stream>>>(
      ybuf, WqkvT, bqkv, qkv, T_SEQ, C3, CDIM, CDIM, SC_F);
  attn_partial<<<dim3(NH, T_SEQ / STRIP_KV, T_SEQ / 128), 256, 0, stream>>>(qkv, pO, pL);
  attn_normalize<<<(T_SEQ * CDIM / 8) / 256, 256, 0, stream>>>(pO, pL, ybuf);
  gemm_bt_bias<128, 2, true, 4><<<dim3(CDIM / 64, T_SEQ / 128), 256, 0, stream>>>(
      ybuf, WprojT, bproj, d_out, T_SEQ, CDIM, CDIM, 0, 1.0f);
}

// Round 20
// 212.340 us; speedup vs baseline: 1.0136x; 1.0018x over previous
//
#include <hip/hip_runtime.h>
#include <hip/hip_bf16.h>

typedef unsigned short u16t;
typedef short bf16x8 __attribute__((ext_vector_type(8)));
typedef short bf16x4 __attribute__((ext_vector_type(4)));
typedef float f32x4 __attribute__((ext_vector_type(4)));

#define T_SEQ 4096
#define NH    12
#define HD    64
#define C3    2304
#define CDIM  768
#define STRIP_KV 1024
#define SLOTS 80          // sum over qt=0..31 of ceil((qt+1)/8)
#define SC_F  0.18033688011112042f   // (1/sqrt(64)) * log2(e), folded into Q

__device__ __forceinline__ float bf2f(u16t u) {
  union { unsigned int i; float f; } c; c.i = ((unsigned int)u) << 16; return c.f;
}
__device__ __forceinline__ u16t f2bf(float f) {
  union { float f; unsigned int i; } c; c.f = f;
  unsigned int u = c.i;
  u += 0x7fffu + ((u >> 16) & 1u);   // RNE
  return (u16t)(u >> 16);
}
// Packed f32x2 -> bf16x2 (v_cvt_pk_bf16_f32 on gfx950); low 16 bits = a.
__device__ __forceinline__ unsigned pk2bf(float a, float b) {
  __hip_bfloat162 h = __float22bfloat162_rn(make_float2(a, b));
  union { __hip_bfloat162 h; unsigned u; } c; c.h = h; return c.u;
}
__device__ __forceinline__ void gload16(const u16t* g, u16t* l) {
  __builtin_amdgcn_global_load_lds((const __attribute__((address_space(1))) void*)g,
                                   (__attribute__((address_space(3))) void*)l,
                                   16, 0, 0);
}

// LDS-only barrier (attn only): in-flight global->VGPR prefetch stays
// outstanding.
#define BARRIER_LGKM() __asm__ __volatile__("s_waitcnt lgkmcnt(0)\n\ts_barrier" ::: "memory")

// ---------------------------------------------------------------------------
// Merged prep: z=0 -> Wqkv transpose, z=1 -> Wproj transpose, z=2 -> x
// fp32->bf16 convert (vectorized float4x2 -> 8 bf16).  Inputs are fp32.
// ---------------------------------------------------------------------------
__global__ __launch_bounds__(256) void prep_inputs(const float* __restrict__ x,
                                                   const float* __restrict__ Wqkv,
                                                   const float* __restrict__ Wproj,
                                                   u16t* __restrict__ xbf,
                                                   u16t* __restrict__ WqkvT,
                                                   u16t* __restrict__ WprojT) {
  const int z = blockIdx.z;
  const int tx = threadIdx.x, ty = threadIdx.y;       // block (32,8)
  if (z == 2) {
    const int t = ty * 32 + tx;
    const int n8 = T_SEQ * CDIM / 8;
    const int i = ((int)blockIdx.y * (int)gridDim.x + (int)blockIdx.x) * 256 + t;
    if (i < n8) {
      const float4 a = ((const float4*)x)[2 * i];
      const float4 b = ((const float4*)x)[2 * i + 1];
      union { uint4 u; unsigned w[4]; } o;
      o.w[0] = pk2bf(a.x, a.y); o.w[1] = pk2bf(a.z, a.w);
      o.w[2] = pk2bf(b.x, b.y); o.w[3] = pk2bf(b.z, b.w);
      ((uint4*)xbf)[i] = o.u;
    }
    return;
  }
  __shared__ u16t tile[32][33];
  const int Cc = z ? CDIM : C3;
  if (z && blockIdx.x >= (unsigned)(CDIM / 32)) return;
  const float* in = z ? Wproj : Wqkv;
  u16t* out = z ? WprojT : WqkvT;
  const int c0 = blockIdx.x * 32, r0 = blockIdx.y * 32;
#pragma unroll
  for (int i = 0; i < 32; i += 8)
    tile[ty + i][tx] = f2bf(in[(size_t)(r0 + ty + i) * Cc + c0 + tx]);
  __syncthreads();
#pragma unroll
  for (int i = 0; i < 32; i += 8)
    out[(size_t)(c0 + ty + i) * CDIM + r0 + tx] = tile[tx][ty + i];
}

// ---------------------------------------------------------------------------
// C[M,N] = A[M,K]*B[K,N] + bias[N]; A,Bt bf16 (Bt row-major [N][K]).
// Tile MT x (32*NF), 256 threads, global_load_lds staging, counted-vmcnt
// DEPTH-buffer pipeline + T2 chunk swizzle.  FINAL: gemm1 DEPTH=3 (4 bufs
// = 64KB = m132 LDS trap at its 2.25/CU grid), gemm2 DEPTH=4 (48KB, grid
// 1.5 blocks/CU -> per-wave ILP is its only latency lever; R19 -2us).
// Steady-state wait vmcnt(2L) at DEPTH=4: 3 stages in flight per wave.
// ---------------------------------------------------------------------------
template <int MT, int NF, bool OUTF32, int DEPTH>
__global__ __launch_bounds__(256) void gemm_bt_bias(
    const u16t* __restrict__ A, const u16t* __restrict__ Bt,
    const float* __restrict__ bias, void* __restrict__ Cout,
    int M, int N, int K, int qcols, float qscale) {
  constexpr int BN = 32 * NF;
  constexpr int MI = MT / 32;          // M fragments per wave
  constexpr int LA = MT / 64;          // per-thread A loads per stage
  constexpr int LB = NF / 2;           // per-thread B loads per stage
  constexpr int L  = LA + LB;          // per-thread loads per stage
  __shared__ u16t lA[DEPTH][MT * 32];
  __shared__ u16t lB[DEPTH][BN * 32];
  const int t = threadIdx.x;
  const int lane = t & 63;
  const int wid  = t >> 6;
  const int quad = lane >> 4, l16 = lane & 15;

  // T1: XCD-aware bijective block swizzle (contiguous tile chunk per XCD).
  const int gx = gridDim.x;
  const int nwg = gx * (int)gridDim.y;
  int bid = (int)blockIdx.y * gx + (int)blockIdx.x;
  if ((nwg & 7) == 0) bid = (bid & 7) * (nwg >> 3) + (bid >> 3);
  const int m0 = (bid / gx) * MT, n0 = (bid % gx) * BN;

  const int wm = (wid >> 1) * (16 * MI), wn = (wid & 1) * (16 * NF);
  // T2 read-side slot: chunk quad of row (16k + l16) lives at slot
  // quad ^ ((l16>>1)&3); *8 elements per chunk.
  const int rswz = (quad ^ ((l16 >> 1) & 3)) * 8;

  f32x4 acc[MI][NF];
#pragma unroll
  for (int i = 0; i < MI; ++i)
#pragma unroll
    for (int j = 0; j < NF; ++j) acc[i][j] = (f32x4){0.f, 0.f, 0.f, 0.f};

  auto stage = [&](int b, int k0) {
#pragma unroll
    for (int rd = 0; rd < LA; ++rd) {
      const int e = rd * 256 + t;
      const int row = e >> 2;
      const int ch  = (e & 3) ^ ((row >> 1) & 3);   // T2 source pre-swizzle
      gload16(A + (size_t)(m0 + row) * K + k0 + ch * 8, &lA[b][e * 8]);
    }
#pragma unroll
    for (int rd = 0; rd < LB; ++rd) {
      const int e = rd * 256 + t;
      const int row = e >> 2;
      const int ch  = (e & 3) ^ ((row >> 1) & 3);
      gload16(Bt + (size_t)(n0 + row) * K + k0 + ch * 8, &lB[b][e * 8]);
    }
  };
  auto compute = [&](int b) {
    bf16x8 af[MI], bfr[NF];
#pragma unroll
    for (int i = 0; i < MI; ++i)
      af[i] = *(const bf16x8*)&lA[b][(wm + i * 16 + l16) * 32 + rswz];
#pragma unroll
    for (int i = 0; i < NF; ++i)
      bfr[i] = *(const bf16x8*)&lB[b][(wn + i * 16 + l16) * 32 + rswz];
#pragma unroll
    for (int i = 0; i < MI; ++i)
#pragma unroll
      for (int j = 0; j < NF; ++j)
        acc[i][j] = __builtin_amdgcn_mfma_f32_16x16x32_bf16(af[i], bfr[j], acc[i][j], 0, 0, 0);
  };

  const int NT = K >> 5;               // K/32 tiles (768 -> 24)
  stage(0, 0);
  stage(1, 32);
  if (DEPTH >= 4 && NT > 2) stage(2, 64);
  for (int tt = 0; tt < NT; ++tt) {
    if (DEPTH >= 4) {
      if (tt < NT - 2) {
        __asm__ __volatile__("s_waitcnt vmcnt(%0)" :: "n"(2 * L) : "memory");
      } else if (tt == NT - 2) {
        __asm__ __volatile__("s_waitcnt vmcnt(%0)" :: "n"(L) : "memory");
      } else {
        __asm__ __volatile__("s_waitcnt vmcnt(0)" ::: "memory");
      }
    } else {
      if (tt < NT - 1) {
        __asm__ __volatile__("s_waitcnt vmcnt(%0)" :: "n"(L) : "memory");
      } else {
        __asm__ __volatile__("s_waitcnt vmcnt(0)" ::: "memory");
      }
    }
    __builtin_amdgcn_s_barrier();
    __builtin_amdgcn_sched_barrier(0);
    compute(tt % DEPTH);
    if (tt + DEPTH - 1 < NT) stage((tt + DEPTH - 1) % DEPTH, (tt + DEPTH - 1) * 32);
  }

#pragma unroll
  for (int j = 0; j < NF; ++j) {
    const int col = n0 + wn + j * 16 + l16;
    const float bv = bias[col];
    const float cs = (col < qcols) ? qscale : 1.0f;
#pragma unroll
    for (int i = 0; i < MI; ++i) {
      const int rowb = m0 + wm + i * 16 + quad * 4;
#pragma unroll
      for (int r = 0; r < 4; ++r) {
        const float val = (acc[i][j][r] + bv) * cs;
        const size_t idx = (size_t)(rowb + r) * N + col;
        if (OUTF32) ((float*)Cout)[idx] = val;
        else        ((u16t*)Cout)[idx] = f2bf(val);
      }
    }
  }
}

// ---------------------------------------------------------------------------
// Split-KV causal attention -- FROZEN at R15/R17 measured best.
// Structure: 256 thr, 4 waves x 32 q-rows, single K/V LDS buffer (22.5 KB,
// VGPR 64), two lgkm barriers per 64-kv tile, setprio around compute,
// STRIP_KV=1024 (slot math a=qt>>3, b=qt&7, base=(a+1)(4a+b)).
// Probed and REJECTED with counter evidence: tighter launch_bounds (R5:
// spill, 4x), K/V dbuf (R10: occupancy halved, +25us), 8-wave/16-row (R14:
// conflicts +60%, +6us), second V-swizzle key (R16: conflicts -32% but
// read-path perturbed, +17us).
// ---------------------------------------------------------------------------
#define KSTR 88
#define VSTR 88

__global__ __launch_bounds__(256, 4) void attn_partial(const u16t* __restrict__ qkv,
                                                       u16t* __restrict__ pO,
                                                       float* __restrict__ pL) {
  const int h     = blockIdx.x;
  const int strip = blockIdx.y;
  const int qt    = 31 - (int)blockIdx.z;           // heavy q-tiles first
  const int q0 = qt * 128;
  const int kv_begin = strip * STRIP_KV;
  const int kv_end   = q0 + 128;
  if (kv_begin >= kv_end) return;                   // strip above diagonal
  const int kv_stop = (kv_begin + STRIP_KV < kv_end) ? kv_begin + STRIP_KV : kv_end;
  const int a = qt >> 3, b = qt & 7;
  const int slot = (a + 1) * (4 * a + b) + strip;

  __shared__ u16t lK[64 * KSTR];        // [kv][d]
  __shared__ u16t lVt[64 * VSTR];       // [d][kv^swz] (reused as epilogue scratch)

  const int t = threadIdx.x;
  const int lane = t & 63;
  const int wid  = t >> 6;
  const int quad = lane >> 4, l16 = lane & 15;
  const int wr = q0 + wid * 32;                     // wave owns 32 q rows

  const int krow = t >> 3, kcol = (t & 7) * 8;
  const int vk0 = 4 * (t >> 4);
  const int vd0 = 4 * (t & 15);
  const int vswz = (t & 3) << 3;
  const u16t* Kbase = qkv + CDIM + h * HD;
  const u16t* Vbase = qkv + 2 * CDIM + h * HD;

  // Q fragments (pre-scaled by SC in gemm1's epilogue)
  bf16x8 qf[2][2];
#pragma unroll
  for (int qn = 0; qn < 2; ++qn) {
    const int row = wr + qn * 16 + l16;
#pragma unroll
    for (int kd = 0; kd < 2; ++kd)
      qf[qn][kd] = *(const bf16x8*)(qkv + (size_t)row * C3 + h * HD + kd * 32 + quad * 8);
  }

  f32x4 oaccT[4][2];                 // O^T tiles: [dn][qn], row=d, col=q
  f32x4 laccT[2];                    // l via ones-MFMA (all 4 regs identical)
#pragma unroll
  for (int dn = 0; dn < 4; ++dn)
#pragma unroll
    for (int qn = 0; qn < 2; ++qn) oaccT[dn][qn] = (f32x4){0.f, 0.f, 0.f, 0.f};
#pragma unroll
  for (int qn = 0; qn < 2; ++qn) laccT[qn] = (f32x4){0.f, 0.f, 0.f, 0.f};
  bf16x4 ones4;
#pragma unroll
  for (int i = 0; i < 4; ++i) ones4[i] = (short)0x3F80;  // bf16 1.0

  const int pswz = ((l16 >> 2) & 3) << 3;          // V read-side swizzle key

  uint4 kreg0, kreg1;
  union { uint2 u; u16t hw[4]; } vreg[4];

#define LOAD_TILE(KV0)                                                        \
  do {                                                                        \
    kreg0 = *(const uint4*)(Kbase + (size_t)((KV0) + krow) * C3 + kcol);      \
    kreg1 = *(const uint4*)(Kbase + (size_t)((KV0) + krow + 32) * C3 + kcol); \
    _Pragma("unroll")                                                         \
    for (int i = 0; i < 4; ++i)                                               \
      vreg[i].u = *(const uint2*)(Vbase + (size_t)((KV0) + vk0 + i) * C3 + vd0); \
  } while (0)

#define STORE_TILE()                                                          \
  do {                                                                        \
    *(uint4*)&lK[krow * KSTR + kcol] = kreg0;                                 \
    *(uint4*)&lK[(krow + 32) * KSTR + kcol] = kreg1;                          \
    _Pragma("unroll")                                                         \
    for (int j = 0; j < 4; ++j) {                                             \
      union { uint2 u; u16t hw[4]; } w;                                       \
      w.hw[0] = vreg[0].hw[j]; w.hw[1] = vreg[1].hw[j];                       \
      w.hw[2] = vreg[2].hw[j]; w.hw[3] = vreg[3].hw[j];                       \
      *(uint2*)&lVt[(vd0 + j) * VSTR + (vk0 ^ vswz)] = w.u;                   \
    }                                                                         \
  } while (0)

  LOAD_TILE(kv_begin);
  STORE_TILE();

  for (int kv0 = kv_begin; kv0 < kv_stop; kv0 += 64) {
    const bool havenext = (kv0 + 64 < kv_stop);
    if (havenext) LOAD_TILE(kv0 + 64);   // stays in flight across compute
    BARRIER_LGKM();

    if (kv0 <= wr + 31) {                // wave-uniform skip of masked tiles
      __builtin_amdgcn_s_setprio(1);
      // ---- S^T = K · Q^T (Q pre-scaled; exp2 arg is ready) ----
      f32x4 sacc[4][2];                  // [kvt][qn]
#pragma unroll
      for (int kvt = 0; kvt < 4; ++kvt) {
        bf16x8 kf0 = *(const bf16x8*)&lK[(kvt * 16 + l16) * KSTR + quad * 8];
        bf16x8 kf1 = *(const bf16x8*)&lK[(kvt * 16 + l16) * KSTR + 32 + quad * 8];
#pragma unroll
        for (int qn = 0; qn < 2; ++qn) {
          f32x4 s = (f32x4){0.f, 0.f, 0.f, 0.f};
          s = __builtin_amdgcn_mfma_f32_16x16x32_bf16(kf0, qf[qn][0], s, 0, 0, 0);
          s = __builtin_amdgcn_mfma_f32_16x16x32_bf16(kf1, qf[qn][1], s, 0, 0, 0);
          sacc[kvt][qn] = s;
        }
      }
      const bool need_mask = (kv0 + 63 > wr);
      // ---- P^T = exp2(S^T) -> packed bf16 B-operand registers ----
      bf16x4 pbf[4][2];
#pragma unroll
      for (int kvt = 0; kvt < 4; ++kvt)
#pragma unroll
        for (int qn = 0; qn < 2; ++qn) {
          const int qg = wr + qn * 16 + l16;
          float pv[4];
#pragma unroll
          for (int r = 0; r < 4; ++r) {
            const int kvg = kv0 + kvt * 16 + quad * 4 + r;
            float p = __builtin_amdgcn_exp2f(sacc[kvt][qn][r]);
            if (need_mask && (kvg > qg)) p = 0.f;
            pv[r] = p;
          }
          union { bf16x4 v; unsigned u[2]; } pw;
          pw.u[0] = pk2bf(pv[0], pv[1]);
          pw.u[1] = pk2bf(pv[2], pv[3]);
          pbf[kvt][qn] = pw.v;
        }
      // ---- O^T += V^T · P^T ; l += ones · P^T (both pure MFMA) ----
#pragma unroll
      for (int kvt = 0; kvt < 4; ++kvt) {
        const int kvcol = (kvt * 16 + quad * 4) ^ pswz;
#pragma unroll
        for (int qn = 0; qn < 2; ++qn)
          laccT[qn] = __builtin_amdgcn_mfma_f32_16x16x16bf16_1k(
              ones4, pbf[kvt][qn], laccT[qn], 0, 0, 0);
#pragma unroll
        for (int dn = 0; dn < 4; ++dn) {
          bf16x4 vf = *(const bf16x4*)&lVt[(dn * 16 + l16) * VSTR + kvcol];
#pragma unroll
          for (int qn = 0; qn < 2; ++qn)
            oaccT[dn][qn] = __builtin_amdgcn_mfma_f32_16x16x16bf16_1k(
                vf, pbf[kvt][qn], oaccT[dn][qn], 0, 0, 0);
        }
      }
      __builtin_amdgcn_s_setprio(0);
    }
    BARRIER_LGKM();                      // all reads of LDS tile kv0 done
    if (havenext) STORE_TILE();
  }

  // ---- epilogue: O^T -> [q][d] via per-wave LDS transpose; packed converts.
  {
    u16t* scr = &lVt[wid * 16 * 80];     // 16 q-rows x stride 80 per wave
    u16t* po = pO + ((size_t)h * SLOTS + slot) * 128 * HD;
    float* pl = pL + ((size_t)h * SLOTS + slot) * 128;
#pragma unroll
    for (int qn = 0; qn < 2; ++qn) {
#pragma unroll
      for (int dn = 0; dn < 4; ++dn) {
        union { bf16x4 v; unsigned u[2]; } w;
        w.u[0] = pk2bf(oaccT[dn][qn][0], oaccT[dn][qn][1]);
        w.u[1] = pk2bf(oaccT[dn][qn][2], oaccT[dn][qn][3]);
        *(bf16x4*)&scr[l16 * 80 + dn * 16 + quad * 4] = w.v;
      }
      __asm__ __volatile__("s_waitcnt lgkmcnt(0)" ::: "memory");
      const int ql = wid * 32 + qn * 16 + l16;
      uint4 w0 = *(const uint4*)&scr[l16 * 80 + quad * 16];
      uint4 w1 = *(const uint4*)&scr[l16 * 80 + quad * 16 + 8];
      u16t* dst = po + (size_t)ql * HD + quad * 16;
      *(uint4*)dst = w0;
      *(uint4*)(dst + 8) = w1;
      if (quad == 0) pl[ql] = laccT[qn][0];
      __asm__ __volatile__("s_waitcnt lgkmcnt(0)" ::: "memory");
    }
  }
#undef LOAD_TILE
#undef STORE_TILE
}

// ---------------------------------------------------------------------------
// 8-wide: each thread normalizes 8 consecutive d of one (q,h).
// STRIP_KV=1024 slot math: a=qt>>3, b=qt&7, base=(a+1)(4a+b), ns=a+1.
// ---------------------------------------------------------------------------
__global__ __launch_bounds__(256) void attn_normalize(const u16t* __restrict__ pO,
                                                      const float* __restrict__ pL,
                                                      u16t* __restrict__ y) {
  const int i = blockIdx.x * 256 + threadIdx.x;   // over T*C/8
  const int q = i / (CDIM / 8), c8 = (i % (CDIM / 8)) * 8;
  const int h = c8 >> 6, d = c8 & 63;
  const int qt = q >> 7, ql = q & 127;
  const int a = qt >> 3, b = qt & 7;
  const int base = (a + 1) * (4 * a + b);
  const int ns = a + 1;                            // ceil((qt+1)/8)
  float o[8] = {0.f, 0.f, 0.f, 0.f, 0.f, 0.f, 0.f, 0.f};
  float l = 0.f;
  for (int s = 0; s < ns; ++s) {
    const size_t sl = (size_t)h * SLOTS + base + s;
    union { uint4 u; u16t hw[8]; } v;
    v.u = *(const uint4*)&pO[(sl * 128 + ql) * HD + d];
#pragma unroll
    for (int j = 0; j < 8; ++j) o[j] += bf2f(v.hw[j]);
    l += pL[sl * 128 + ql];
  }
  const float rl = 1.0f / l;
  union { uint4 u; unsigned w[4]; } wv;
#pragma unroll
  for (int j = 0; j < 4; ++j)
    wv.w[j] = pk2bf(o[2 * j] * rl, o[2 * j + 1] * rl);
  *(uint4*)&y[(size_t)q * CDIM + c8] = wv.u;
}

// ---------------------------------------------------------------------------
extern "C" void kernel_launch(void* const* d_in, const int* in_sizes, int n_in,
                              void* d_out, int out_size, void* d_ws, size_t ws_size,
                              hipStream_t stream) {
  const float* x     = (const float*)d_in[0];
  // d_in[1] = mask (unused — causal mask applied analytically)
  const float* Wqkv  = (const float*)d_in[2];
  const float* bqkv  = (const float*)d_in[3];
  const float* Wproj = (const float*)d_in[4];
  const float* bproj = (const float*)d_in[5];

  u16t* qkv    = (u16t*)d_ws;                     // [4096][2304] bf16
  u16t* ybuf   = qkv    + (size_t)T_SEQ * C3;     // [4096][768]  bf16 (x, then attn out)
  u16t* WqkvT  = ybuf   + (size_t)T_SEQ * CDIM;   // [2304][768]  bf16
  u16t* WprojT = WqkvT  + (size_t)C3 * CDIM;      // [768][768]   bf16
  u16t* pO     = WprojT + (size_t)CDIM * CDIM;    // [12][80][128][64] bf16
  float* pL    = (float*)(pO + (size_t)NH * SLOTS * 128 * HD);  // [12][80][128] f32

  prep_inputs<<<dim3(C3 / 32, CDIM / 32, 3), dim3(32, 8), 0, stream>>>(
      x, Wqkv, Wproj, ybuf, WqkvT, WprojT);
  gemm_bt_bias<128, 4, false, 3><<<dim3(C3 / 128, T_SEQ / 128), 256, 0, stream>>>(
      ybuf, WqkvT, bqkv, qkv, T_SEQ, C3, CDIM, CDIM, SC_F);
  attn_partial<<<dim3(NH, T_SEQ / STRIP_KV, T_SEQ / 128), 256, 0, stream>>>(qkv, pO, pL);
  attn_normalize<<<(T_SEQ * CDIM / 8) / 256, 256, 0, stream>>>(pO, pL, ybuf);
  gemm_bt_bias<128, 2, true, 4><<<dim3(CDIM / 64, T_SEQ / 128), 256, 0, stream>>>(
      ybuf, WprojT, bproj, d_out, T_SEQ, CDIM, CDIM, 0, 1.0f);
}